// Round 1
// 715.632 us; speedup vs baseline: 1.6446x; 1.6446x over previous
//
#include <hip/hip_runtime.h>
#include <hip/hip_bf16.h>
#include <stdint.h>
#include <stddef.h>

// Problem constants (from reference): T=2048, B=16, D=1024. ALL I/O = float32.
#define T_DIM 2048
#define B_DIM 16
#define D_DIM 1024
#define BD    (B_DIM * D_DIM)          // 16384 state elements
#define TBD   ((size_t)T_DIM * BD)     // 33554432
#define CHUNKS 32                      // parallel-scan chunks over T
#define TC    (T_DIM / CHUNKS)         // 64 steps per chunk

using bf16 = __hip_bfloat16;
typedef __attribute__((ext_vector_type(8))) short short8;   // 8 x bf16 = 4 VGPRs
typedef __attribute__((ext_vector_type(4))) float f32x4;

// f32 -> bf16 bits, round-to-nearest-even (finite inputs).
__device__ __forceinline__ unsigned f2bf(float f) {
    unsigned u = __float_as_uint(f);
    return (u + 0x7FFFu + ((u >> 16) & 1u)) >> 16;
}

// ---------------------------------------------------------------------------
// f32 buffer -> bf16 buffer (for MFMA operands). 8 elems/thread.
// ---------------------------------------------------------------------------
__global__ __launch_bounds__(256) void cvt_f32_bf16(
    const float* __restrict__ src, short* __restrict__ dst, int n8)
{
    int i = blockIdx.x * 256 + threadIdx.x;
    if (i >= n8) return;
    const float* p = src + (size_t)i * 8;
    f32x4 a = *(const f32x4*)p;
    f32x4 b = *(const f32x4*)(p + 4);
    short8 r;
    r[0] = (short)f2bf(a[0]); r[1] = (short)f2bf(a[1]);
    r[2] = (short)f2bf(a[2]); r[3] = (short)f2bf(a[3]);
    r[4] = (short)f2bf(b[0]); r[5] = (short)f2bf(b[1]);
    r[6] = (short)f2bf(b[2]); r[7] = (short)f2bf(b[3]);
    *(short8*)(dst + (size_t)i * 8) = r;
}

// ---------------------------------------------------------------------------
// async global->LDS, 16B per lane. LDS dest is wave-uniform base + lane*16.
// ---------------------------------------------------------------------------
typedef __attribute__((address_space(1))) void gvoid;
typedef __attribute__((address_space(3))) void lvoid;
__device__ __forceinline__ void gload_lds16(const short* g, short* l) {
    __builtin_amdgcn_global_load_lds((gvoid*)g, (lvoid*)l, 16, 0, 0);
}

// ---------------------------------------------------------------------------
// Fused K/V projection GEMM, m97 structure: 128x128 tile, BK=32, LDS
// double-buffered via global_load_lds width=16, ds_read_b128 fragments,
// one __syncthreads per K-step (its vmcnt/lgkm drain is the pipeline sync).
//   pre[m][n] = sum_d x[m][d]*W[n][d]  (NT, both row-major K-fast)
//   z==0: k = sigmoid(pre+b_k); z==1: v = tanh(pre+b_v)
// Fragment maps (verified in prior session's direct-global kernel, preserved):
//   A: row = l&15 (+16*mt +64*wm), k = (l>>4)*8+j ; B: same with n
//   C/D: col = l&15, row = (l>>4)*4 + r
// ---------------------------------------------------------------------------
__global__ __launch_bounds__(256) void gemm_kv_bf16(
    const short* __restrict__ xb,
    const short* __restrict__ Wkb, const float* __restrict__ bk,
    const short* __restrict__ Wvb, const float* __restrict__ bv,
    float* __restrict__ kout, float* __restrict__ vout)
{
    __shared__ short sA[2][128 * 32];   // 8KB per buffer
    __shared__ short sB[2][128 * 32];

    const int tid  = threadIdx.x;
    const int lane = tid & 63;
    const int wave = tid >> 6;
    const int wm   = wave & 1;
    const int wn   = wave >> 1;
    const int quad = lane >> 4;
    const int l15  = lane & 15;

    const int blkn = blockIdx.x;      // 0..7
    const int blkm = blockIdx.y;      // 0..255
    const bool is_k = (blockIdx.z == 0);

    const short* W    = is_k ? Wkb : Wvb;
    const float* bias = is_k ? bk : bv;
    float*       outp = is_k ? kout : vout;

    const int m0 = blkm * 128;
    const int n0 = blkn * 128;

    // Staging geometry: per call, each of 4 waves writes 16 rows x 64B
    // (lane covers row=lane>>2, 16B chunk=(lane&3)*8 shorts). Two calls
    // per 128-row tile (halves of 64 rows).
    const int srow = wave * 16 + (lane >> 2);        // 0..63 within half
    const int skof = (lane & 3) * 8;                 // shorts
    const short* ga = xb + (size_t)(m0 + srow) * D_DIM + skof;
    const short* gb = W  + (size_t)(n0 + srow) * D_DIM + skof;
    const int lofs = wave * 512;                     // wave*16 rows * 32 shorts

    auto STAGE = [&](int buf, int ks) {
        const size_t ko = (size_t)ks * 32;
        gload_lds16(ga + ko,                        &sA[buf][lofs]);
        gload_lds16(ga + ko + (size_t)64 * D_DIM,   &sA[buf][2048 + lofs]);
        gload_lds16(gb + ko,                        &sB[buf][lofs]);
        gload_lds16(gb + ko + (size_t)64 * D_DIM,   &sB[buf][2048 + lofs]);
    };

    f32x4 acc[4][4] = {};

    STAGE(0, 0);
    int cur = 0;
    for (int ks = 0; ks < D_DIM / 32; ++ks) {
        // Drains vmcnt (stage of `cur` complete) and lgkm (all waves' reads
        // of `cur^1` complete) before any wave proceeds.
        __syncthreads();
        if (ks + 1 < D_DIM / 32) STAGE(cur ^ 1, ks + 1);

        const short* lA = sA[cur];
        const short* lB = sB[cur];
        short8 a[4], b[4];
#pragma unroll
        for (int mt = 0; mt < 4; ++mt)
            a[mt] = *(const short8*)&lA[(wm * 64 + mt * 16 + l15) * 32 + quad * 8];
#pragma unroll
        for (int nt = 0; nt < 4; ++nt)
            b[nt] = *(const short8*)&lB[(wn * 64 + nt * 16 + l15) * 32 + quad * 8];
#pragma unroll
        for (int mt = 0; mt < 4; ++mt)
#pragma unroll
            for (int nt = 0; nt < 4; ++nt)
                acc[mt][nt] = __builtin_amdgcn_mfma_f32_16x16x32_bf16(
                    a[mt], b[nt], acc[mt][nt], 0, 0, 0);
        cur ^= 1;
    }

    const int gm0 = blkm * 128 + wm * 64 + quad * 4;
    const int gn  = blkn * 128 + wn * 64 + l15;
#pragma unroll
    for (int nt = 0; nt < 4; ++nt) {
        const int n = gn + nt * 16;
        const float bs = bias[n];
#pragma unroll
        for (int mt = 0; mt < 4; ++mt) {
            const int m = gm0 + mt * 16;
#pragma unroll
            for (int r = 0; r < 4; ++r) {
                float pre = acc[mt][nt][r] + bs;
                pre = fminf(20.f, fmaxf(-20.f, pre));
                float o;
                if (is_k) o = 1.f / (1.f + __expf(-pre));                // sigmoid
                else      o = 2.f / (1.f + __expf(-2.f * pre)) - 1.f;    // tanh
                outp[(size_t)(m + r) * D_DIM + n] = o;
            }
        }
    }
}

// ---------------------------------------------------------------------------
// Fallback GEMM when ws too small: load f32 operands, convert in-kernel.
// ---------------------------------------------------------------------------
__device__ __forceinline__ short8 load_cvt8(const float* p) {
    f32x4 a = *(const f32x4*)p;
    f32x4 b = *(const f32x4*)(p + 4);
    short8 r;
    r[0] = (short)f2bf(a[0]); r[1] = (short)f2bf(a[1]);
    r[2] = (short)f2bf(a[2]); r[3] = (short)f2bf(a[3]);
    r[4] = (short)f2bf(b[0]); r[5] = (short)f2bf(b[1]);
    r[6] = (short)f2bf(b[2]); r[7] = (short)f2bf(b[3]);
    return r;
}

__global__ __launch_bounds__(256) void gemm_kv_f32src(
    const float* __restrict__ x,
    const float* __restrict__ Wk, const float* __restrict__ bk,
    const float* __restrict__ Wv, const float* __restrict__ bv,
    float* __restrict__ kout, float* __restrict__ vout)
{
    const int tid  = threadIdx.x;
    const int lane = tid & 63;
    const int wave = tid >> 6;
    const int wm   = wave & 1;
    const int wn   = wave >> 1;
    const int quad = lane >> 4;
    const int l15  = lane & 15;

    const int blkn = blockIdx.x;
    const int blkm = blockIdx.y;
    const bool is_k = (blockIdx.z == 0);

    const float* W    = is_k ? Wk : Wv;
    const float* bias = is_k ? bk : bv;
    float*       outp = is_k ? kout : vout;

    const int m0 = blkm * 128 + wm * 64;
    const int n0 = blkn * 128 + wn * 64;

    const float* ap = x + (size_t)(m0 + l15) * D_DIM + quad * 8;
    const float* bp = W + (size_t)(n0 + l15) * D_DIM + quad * 8;

    f32x4 acc[4][4] = {};

    for (int ks = 0; ks < D_DIM / 32; ++ks) {
        short8 a[4], b[4];
#pragma unroll
        for (int mt = 0; mt < 4; ++mt)
            a[mt] = load_cvt8(ap + (size_t)mt * 16 * D_DIM + ks * 32);
#pragma unroll
        for (int nt = 0; nt < 4; ++nt)
            b[nt] = load_cvt8(bp + (size_t)nt * 16 * D_DIM + ks * 32);
#pragma unroll
        for (int mt = 0; mt < 4; ++mt)
#pragma unroll
            for (int nt = 0; nt < 4; ++nt)
                acc[mt][nt] = __builtin_amdgcn_mfma_f32_16x16x32_bf16(
                    a[mt], b[nt], acc[mt][nt], 0, 0, 0);
    }

    const int gm0 = blkm * 128 + wm * 64 + quad * 4;
    const int gn  = blkn * 128 + wn * 64 + l15;
#pragma unroll
    for (int nt = 0; nt < 4; ++nt) {
        const int n = gn + nt * 16;
        const float bs = bias[n];
#pragma unroll
        for (int mt = 0; mt < 4; ++mt) {
            const int m = gm0 + mt * 16;
#pragma unroll
            for (int r = 0; r < 4; ++r) {
                float pre = acc[mt][nt][r] + bs;
                pre = fminf(20.f, fmaxf(-20.f, pre));
                float o;
                if (is_k) o = 1.f / (1.f + __expf(-pre));
                else      o = 2.f / (1.f + __expf(-2.f * pre)) - 1.f;
                outp[(size_t)(m + r) * D_DIM + n] = o;
            }
        }
    }
}

// ---------------------------------------------------------------------------
// Chunked parallel scan of the linear recurrence h_t = a_t h_{t-1} + b_t,
// a_t = 1-k_t, b_t = k_t v_t. Three phases:
//   A: per (chunk, channel), compose the chunk transform (A, Bv).
//   B: tiny sequential scan over the 32 chunk transforms -> Hinit per chunk.
//   C: per (chunk, channel), replay with known Hinit; write h and out.
// kw aliases outp, vw aliases hsec+BD: phase A is read-only; phase C reads
// every slot strictly before the same thread overwrites it (data-dependent),
// so element-exact in-place RMW stays safe.
// ---------------------------------------------------------------------------
__global__ __launch_bounds__(256) void scan_phase_a(
    const float* kw, const float* vw,
    float* __restrict__ Aab, float* __restrict__ Bab)
{
    const int bd = blockIdx.x * 256 + threadIdx.x;   // 0..BD-1
    const int c  = blockIdx.y;                       // 0..CHUNKS-1
    const float* kp = kw + (size_t)(c * TC) * BD + bd;
    const float* vp = vw + (size_t)(c * TC) * BD + bd;

    float A = 1.f, Bv = 0.f;
    for (int t0 = 0; t0 < TC; t0 += 8) {
        float kk[8], vv[8];
#pragma unroll
        for (int j = 0; j < 8; ++j) {
            kk[j] = kp[(size_t)(t0 + j) * BD];
            vv[j] = vp[(size_t)(t0 + j) * BD];
        }
#pragma unroll
        for (int j = 0; j < 8; ++j) {
            const float a = 1.f - kk[j];
            A  = A * a;
            Bv = a * Bv + kk[j] * vv[j];
        }
    }
    Aab[(size_t)c * BD + bd] = A;
    Bab[(size_t)c * BD + bd] = Bv;
}

__global__ __launch_bounds__(256) void scan_phase_b(
    const float* __restrict__ h0,
    const float* __restrict__ Aab, const float* __restrict__ Bab,
    float* __restrict__ Hinit, float* hsec)
{
    const int bd = blockIdx.x * 256 + threadIdx.x;   // 0..BD-1
    float h = h0[bd];
    hsec[bd] = h;                                    // h[0] = h0
#pragma unroll
    for (int c = 0; c < CHUNKS; ++c) {
        Hinit[(size_t)c * BD + bd] = h;
        h = Aab[(size_t)c * BD + bd] * h + Bab[(size_t)c * BD + bd];
    }
}

__global__ __launch_bounds__(256) void scan_phase_c(
    const float* kw, const float* vw, const float* __restrict__ Hinit,
    float* outp, float* hsec)
{
    const int bd = blockIdx.x * 256 + threadIdx.x;   // 0..BD-1
    const int c  = blockIdx.y;                       // 0..CHUNKS-1
    float h = Hinit[(size_t)c * BD + bd];

    const float* kp = kw + (size_t)(c * TC) * BD + bd;
    const float* vp = vw + (size_t)(c * TC) * BD + bd;
    float* op = outp + (size_t)(c * TC) * BD + bd;
    float* hp = hsec + (size_t)(c * TC + 1) * BD + bd;

    for (int t0 = 0; t0 < TC; t0 += 8) {
        float kk[8], vv[8];
#pragma unroll
        for (int j = 0; j < 8; ++j) {
            kk[j] = kp[(size_t)(t0 + j) * BD];
            vv[j] = vp[(size_t)(t0 + j) * BD];
        }
#pragma unroll
        for (int j = 0; j < 8; ++j) {
            h = (1.f - kk[j]) * h + kk[j] * vv[j];
            hp[(size_t)(t0 + j) * BD] = h;
            const float sig = 1.f / (1.f + __expf(-h));
            op[(size_t)(t0 + j) * BD] = h * h * sig;
        }
    }
}

// ---------------------------------------------------------------------------
// Fallback sequential scan (ws too small for chunk buffers).
// ---------------------------------------------------------------------------
__global__ __launch_bounds__(64) void scan_kernel(
    const float* kw, const float* vw, const float* h0,
    float* outp, float* hsec)
{
    const int c = blockIdx.x * 64 + threadIdx.x;   // 0..16383
    float h = h0[c];
    hsec[c] = h;

    const float* kp = kw + c;
    const float* vp = vw + c;
    float* op = outp + c;
    float* hp = hsec + BD + c;

    for (int t = 0; t < T_DIM; t += 8) {
        float kk[8], vv[8];
#pragma unroll
        for (int j = 0; j < 8; ++j) {
            kk[j] = kp[(size_t)(t + j) * BD];
            vv[j] = vp[(size_t)(t + j) * BD];
        }
#pragma unroll
        for (int j = 0; j < 8; ++j) {
            h = (1.f - kk[j]) * h + kk[j] * vv[j];
            hp[(size_t)(t + j) * BD] = h;
            const float sig = 1.f / (1.f + __expf(-h));
            op[(size_t)(t + j) * BD] = h * h * sig;
        }
    }
}

// ---------------------------------------------------------------------------
extern "C" void kernel_launch(void* const* d_in, const int* in_sizes, int n_in,
                              void* d_out, int out_size, void* d_ws, size_t ws_size,
                              hipStream_t stream)
{
    const float* x  = (const float*)d_in[0];   // [T,B,D]
    const float* h0 = (const float*)d_in[1];   // [B,D]
    const float* Wk = (const float*)d_in[2];   // [D,D]
    const float* bk = (const float*)d_in[3];   // [D]
    const float* Wv = (const float*)d_in[4];   // [D,D]
    const float* bv = (const float*)d_in[5];   // [D]

    float* outp = (float*)d_out;               // output section [T,B,D]
    float* hsec = outp + TBD;                  // h section [T+1,B,D]

    // k -> output section, v -> h[1:] section: element-exact in-place (safe,
    // see scan comments). No workspace needed for k/v themselves.
    float* kw = outp;
    float* vw = hsec + BD;

    const size_t bf16_bytes = (TBD + 2 * (size_t)D_DIM * D_DIM) * sizeof(short);
    const size_t scan_bytes = 3 * (size_t)CHUNKS * BD * sizeof(float);

    bool bf16_path = false, chunked = false;
    float* Aab = nullptr;
    if (ws_size >= bf16_bytes + scan_bytes) {
        bf16_path = true; chunked = true;
        Aab = (float*)((char*)d_ws + bf16_bytes);
    } else if (ws_size >= bf16_bytes) {
        bf16_path = true;
    } else if (ws_size >= scan_bytes) {
        chunked = true;
        Aab = (float*)d_ws;
    }
    float* Bab   = chunked ? Aab + (size_t)CHUNKS * BD : nullptr;
    float* Hinit = chunked ? Bab + (size_t)CHUNKS * BD : nullptr;

    if (bf16_path) {
        short* xb  = (short*)d_ws;                       // [T*B, D] bf16
        short* Wkb = xb + TBD;                           // [D, D] bf16
        short* Wvb = Wkb + (size_t)D_DIM * D_DIM;
        cvt_f32_bf16<<<dim3((int)(TBD / 8 / 256)), 256, 0, stream>>>(x, xb, (int)(TBD / 8));
        cvt_f32_bf16<<<dim3(D_DIM * D_DIM / 8 / 256), 256, 0, stream>>>(Wk, Wkb, D_DIM * D_DIM / 8);
        cvt_f32_bf16<<<dim3(D_DIM * D_DIM / 8 / 256), 256, 0, stream>>>(Wv, Wvb, D_DIM * D_DIM / 8);
        gemm_kv_bf16<<<dim3(8, 256, 2), 256, 0, stream>>>(xb, Wkb, bk, Wvb, bv, kw, vw);
    } else {
        gemm_kv_f32src<<<dim3(8, 256, 2), 256, 0, stream>>>(x, Wk, bk, Wv, bv, kw, vw);
    }

    if (chunked) {
        scan_phase_a<<<dim3(BD / 256, CHUNKS), 256, 0, stream>>>(kw, vw, Aab, Bab);
        scan_phase_b<<<dim3(BD / 256), 256, 0, stream>>>(h0, Aab, Bab, Hinit, hsec);
        scan_phase_c<<<dim3(BD / 256, CHUNKS), 256, 0, stream>>>(kw, vw, Hinit, outp, hsec);
    } else {
        scan_kernel<<<dim3(BD / 64), 64, 0, stream>>>(kw, vw, h0, outp, hsec);
    }
}

// Round 2
// 702.830 us; speedup vs baseline: 1.6745x; 1.0182x over previous
//
#include <hip/hip_runtime.h>
#include <hip/hip_bf16.h>
#include <stdint.h>
#include <stddef.h>

// Problem constants (from reference): T=2048, B=16, D=1024. ALL I/O = float32.
#define T_DIM 2048
#define B_DIM 16
#define D_DIM 1024
#define BD    (B_DIM * D_DIM)          // 16384 state elements
#define TBD   ((size_t)T_DIM * BD)     // 33554432

using bf16 = __hip_bfloat16;
typedef __attribute__((ext_vector_type(8))) short short8;   // 8 x bf16 = 4 VGPRs
typedef __attribute__((ext_vector_type(4))) float f32x4;

// f32 -> bf16 bits, round-to-nearest-even (finite inputs).
__device__ __forceinline__ unsigned f2bf(float f) {
    unsigned u = __float_as_uint(f);
    return (u + 0x7FFFu + ((u >> 16) & 1u)) >> 16;
}

// ---------------------------------------------------------------------------
// f32 buffer -> bf16 buffer (for MFMA operands). 8 elems/thread.
// ---------------------------------------------------------------------------
__global__ __launch_bounds__(256) void cvt_f32_bf16(
    const float* __restrict__ src, short* __restrict__ dst, int n8)
{
    int i = blockIdx.x * 256 + threadIdx.x;
    if (i >= n8) return;
    const float* p = src + (size_t)i * 8;
    f32x4 a = *(const f32x4*)p;
    f32x4 b = *(const f32x4*)(p + 4);
    short8 r;
    r[0] = (short)f2bf(a[0]); r[1] = (short)f2bf(a[1]);
    r[2] = (short)f2bf(a[2]); r[3] = (short)f2bf(a[3]);
    r[4] = (short)f2bf(b[0]); r[5] = (short)f2bf(b[1]);
    r[6] = (short)f2bf(b[2]); r[7] = (short)f2bf(b[3]);
    *(short8*)(dst + (size_t)i * 8) = r;
}

// ---------------------------------------------------------------------------
// async global->LDS, 16B per lane. LDS dest is wave-uniform base + lane*16.
// ---------------------------------------------------------------------------
typedef __attribute__((address_space(1))) void gvoid;
typedef __attribute__((address_space(3))) void lvoid;
__device__ __forceinline__ void gload_lds16(const short* g, short* l) {
    __builtin_amdgcn_global_load_lds((gvoid*)g, (lvoid*)l, 16, 0, 0);
}

// ---------------------------------------------------------------------------
// Fused K/V projection GEMM, m97 structure: 128x128 tile, BK=32, LDS
// double-buffered via global_load_lds width=16, ds_read_b128 fragments,
// one __syncthreads per K-step. XCD-chunked block swizzle (T1): each XCD
// gets a contiguous (z, blkm) range so the 8 blkn blocks sharing an x-panel
// hit the same per-XCD L2 (cuts x over-fetch ~4x -> ~1x).
//   pre[m][n] = sum_d x[m][d]*W[n][d]  (NT, both row-major K-fast)
//   z==0: k = sigmoid(pre+b_k); z==1: v = tanh(pre+b_v)
// Fragment maps (harness-verified in prior rounds, preserved):
//   A: row = l&15 (+16*mt +64*wm), k = (l>>4)*8+j ; B: same with n
//   C/D: col = l&15, row = (l>>4)*4 + r
// ---------------------------------------------------------------------------
__global__ __launch_bounds__(256, 4) void gemm_kv_bf16(
    const short* __restrict__ xb,
    const short* __restrict__ Wkb, const float* __restrict__ bk,
    const short* __restrict__ Wvb, const float* __restrict__ bv,
    float* __restrict__ kout, float* __restrict__ vout)
{
    __shared__ short sA[2][128 * 32];   // 8KB per buffer
    __shared__ short sB[2][128 * 32];

    const int tid  = threadIdx.x;
    const int lane = tid & 63;
    const int wave = tid >> 6;
    const int wm   = wave & 1;
    const int wn   = wave >> 1;
    const int quad = lane >> 4;
    const int l15  = lane & 15;

    // XCD-chunked swizzle: dispatch index lin -> logical tile swz.
    // nwg=4096, 8 XCDs, 512 tiles per XCD (bijective since 4096%8==0).
    const int lin = blockIdx.x + (blockIdx.y << 3) + (blockIdx.z << 11);
    const int swz = ((lin & 7) << 9) | (lin >> 3);
    const bool is_k = (swz >> 11) == 0;
    const int blkm = (swz >> 3) & 255;   // 0..255
    const int blkn = swz & 7;            // 0..7

    const short* W    = is_k ? Wkb : Wvb;
    const float* bias = is_k ? bk : bv;
    float*       outp = is_k ? kout : vout;

    const int m0 = blkm * 128;
    const int n0 = blkn * 128;

    // Staging geometry: per call, each of 4 waves writes 16 rows x 64B
    // (lane covers row=lane>>2, 16B chunk=(lane&3)*8 shorts). Two calls
    // per 128-row tile (halves of 64 rows).
    const int srow = wave * 16 + (lane >> 2);        // 0..63 within half
    const int skof = (lane & 3) * 8;                 // shorts
    const short* ga = xb + (size_t)(m0 + srow) * D_DIM + skof;
    const short* gb = W  + (size_t)(n0 + srow) * D_DIM + skof;
    const int lofs = wave * 512;                     // wave*16 rows * 32 shorts

    auto STAGE = [&](int buf, int ks) {
        const size_t ko = (size_t)ks * 32;
        gload_lds16(ga + ko,                        &sA[buf][lofs]);
        gload_lds16(ga + ko + (size_t)64 * D_DIM,   &sA[buf][2048 + lofs]);
        gload_lds16(gb + ko,                        &sB[buf][lofs]);
        gload_lds16(gb + ko + (size_t)64 * D_DIM,   &sB[buf][2048 + lofs]);
    };

    f32x4 acc[4][4] = {};

    STAGE(0, 0);
    int cur = 0;
    for (int ks = 0; ks < D_DIM / 32; ++ks) {
        // Drains vmcnt (stage of `cur` complete) and lgkm (all waves' reads
        // of `cur^1` complete) before any wave proceeds.
        __syncthreads();
        if (ks + 1 < D_DIM / 32) STAGE(cur ^ 1, ks + 1);

        const short* lA = sA[cur];
        const short* lB = sB[cur];
        short8 a[4], b[4];
#pragma unroll
        for (int mt = 0; mt < 4; ++mt)
            a[mt] = *(const short8*)&lA[(wm * 64 + mt * 16 + l15) * 32 + quad * 8];
#pragma unroll
        for (int nt = 0; nt < 4; ++nt)
            b[nt] = *(const short8*)&lB[(wn * 64 + nt * 16 + l15) * 32 + quad * 8];
#pragma unroll
        for (int mt = 0; mt < 4; ++mt)
#pragma unroll
            for (int nt = 0; nt < 4; ++nt)
                acc[mt][nt] = __builtin_amdgcn_mfma_f32_16x16x32_bf16(
                    a[mt], b[nt], acc[mt][nt], 0, 0, 0);
        cur ^= 1;
    }

    const int gm0 = blkm * 128 + wm * 64 + quad * 4;
    const int gn  = blkn * 128 + wn * 64 + l15;
#pragma unroll
    for (int nt = 0; nt < 4; ++nt) {
        const int n = gn + nt * 16;
        const float bs = bias[n];
#pragma unroll
        for (int mt = 0; mt < 4; ++mt) {
            const int m = gm0 + mt * 16;
#pragma unroll
            for (int r = 0; r < 4; ++r) {
                float pre = acc[mt][nt][r] + bs;
                pre = fminf(20.f, fmaxf(-20.f, pre));
                float o;
                if (is_k) o = 1.f / (1.f + __expf(-pre));                // sigmoid
                else      o = 2.f / (1.f + __expf(-2.f * pre)) - 1.f;    // tanh
                outp[(size_t)(m + r) * D_DIM + n] = o;
            }
        }
    }
}

// ---------------------------------------------------------------------------
// Fallback GEMM when ws too small: load f32 operands, convert in-kernel.
// ---------------------------------------------------------------------------
__device__ __forceinline__ short8 load_cvt8(const float* p) {
    f32x4 a = *(const f32x4*)p;
    f32x4 b = *(const f32x4*)(p + 4);
    short8 r;
    r[0] = (short)f2bf(a[0]); r[1] = (short)f2bf(a[1]);
    r[2] = (short)f2bf(a[2]); r[3] = (short)f2bf(a[3]);
    r[4] = (short)f2bf(b[0]); r[5] = (short)f2bf(b[1]);
    r[6] = (short)f2bf(b[2]); r[7] = (short)f2bf(b[3]);
    return r;
}

__global__ __launch_bounds__(256) void gemm_kv_f32src(
    const float* __restrict__ x,
    const float* __restrict__ Wk, const float* __restrict__ bk,
    const float* __restrict__ Wv, const float* __restrict__ bv,
    float* __restrict__ kout, float* __restrict__ vout)
{
    const int tid  = threadIdx.x;
    const int lane = tid & 63;
    const int wave = tid >> 6;
    const int wm   = wave & 1;
    const int wn   = wave >> 1;
    const int quad = lane >> 4;
    const int l15  = lane & 15;

    const int blkn = blockIdx.x;
    const int blkm = blockIdx.y;
    const bool is_k = (blockIdx.z == 0);

    const float* W    = is_k ? Wk : Wv;
    const float* bias = is_k ? bk : bv;
    float*       outp = is_k ? kout : vout;

    const int m0 = blkm * 128 + wm * 64;
    const int n0 = blkn * 128 + wn * 64;

    const float* ap = x + (size_t)(m0 + l15) * D_DIM + quad * 8;
    const float* bp = W + (size_t)(n0 + l15) * D_DIM + quad * 8;

    f32x4 acc[4][4] = {};

    for (int ks = 0; ks < D_DIM / 32; ++ks) {
        short8 a[4], b[4];
#pragma unroll
        for (int mt = 0; mt < 4; ++mt)
            a[mt] = load_cvt8(ap + (size_t)mt * 16 * D_DIM + ks * 32);
#pragma unroll
        for (int nt = 0; nt < 4; ++nt)
            b[nt] = load_cvt8(bp + (size_t)nt * 16 * D_DIM + ks * 32);
#pragma unroll
        for (int mt = 0; mt < 4; ++mt)
#pragma unroll
            for (int nt = 0; nt < 4; ++nt)
                acc[mt][nt] = __builtin_amdgcn_mfma_f32_16x16x32_bf16(
                    a[mt], b[nt], acc[mt][nt], 0, 0, 0);
    }

    const int gm0 = blkm * 128 + wm * 64 + quad * 4;
    const int gn  = blkn * 128 + wn * 64 + l15;
#pragma unroll
    for (int nt = 0; nt < 4; ++nt) {
        const int n = gn + nt * 16;
        const float bs = bias[n];
#pragma unroll
        for (int mt = 0; mt < 4; ++mt) {
            const int m = gm0 + mt * 16;
#pragma unroll
            for (int r = 0; r < 4; ++r) {
                float pre = acc[mt][nt][r] + bs;
                pre = fminf(20.f, fmaxf(-20.f, pre));
                float o;
                if (is_k) o = 1.f / (1.f + __expf(-pre));
                else      o = 2.f / (1.f + __expf(-2.f * pre)) - 1.f;
                outp[(size_t)(m + r) * D_DIM + n] = o;
            }
        }
    }
}

// ---------------------------------------------------------------------------
// Chunked parallel scan of h_t = (1-k_t) h_{t-1} + k_t v_t, runtime chunk
// count nc (tc = T/nc, multiple of 16). Three phases:
//   A: per (chunk, channel), compose chunk transform (A, Bv).
//   B: sequential over nc chunk transforms -> Hinit per chunk (loads batched
//      16-deep so the 1-wave/CU kernel is not one-HBM-latency-per-step).
//   C: per (chunk, channel), replay with known Hinit; write h and out.
// kw aliases outp, vw aliases hsec+BD: phase A is read-only; phase C reads
// every slot strictly before the same thread overwrites it. Phase C manually
// prefetches the next 16 (k,v) BEFORE the current stores: addresses are
// provably disjoint (different t), and program order keeps the loads above
// the stores (compiler cannot sink loads past may-alias stores), so loads
// stay in flight across compute+stores instead of serializing per batch.
// ---------------------------------------------------------------------------
__global__ __launch_bounds__(256) void scan_phase_a(
    const float* kw, const float* vw,
    float* __restrict__ Aab, float* __restrict__ Bab, int tc)
{
    const int bd = blockIdx.x * 256 + threadIdx.x;   // 0..BD-1
    const int c  = blockIdx.y;                       // 0..nc-1
    const float* kp = kw + (size_t)c * tc * BD + bd;
    const float* vp = vw + (size_t)c * tc * BD + bd;

    float A = 1.f, Bv = 0.f;
    for (int t0 = 0; t0 < tc; t0 += 16) {
        float kk[16], vv[16];
#pragma unroll
        for (int j = 0; j < 16; ++j) {
            kk[j] = kp[(size_t)(t0 + j) * BD];
            vv[j] = vp[(size_t)(t0 + j) * BD];
        }
#pragma unroll
        for (int j = 0; j < 16; ++j) {
            const float a = 1.f - kk[j];
            A  = A * a;
            Bv = a * Bv + kk[j] * vv[j];
        }
    }
    Aab[(size_t)c * BD + bd] = A;
    Bab[(size_t)c * BD + bd] = Bv;
}

__global__ __launch_bounds__(256) void scan_phase_b(
    const float* __restrict__ h0,
    const float* __restrict__ Aab, const float* __restrict__ Bab,
    float* __restrict__ Hinit, float* hsec, int nc)
{
    const int bd = blockIdx.x * 256 + threadIdx.x;   // 0..BD-1
    float h = h0[bd];
    hsec[bd] = h;                                    // h[0] = h0
    for (int c0 = 0; c0 < nc; c0 += 16) {
        float aa[16], bb[16];
#pragma unroll
        for (int j = 0; j < 16; ++j) {
            aa[j] = Aab[(size_t)(c0 + j) * BD + bd];
            bb[j] = Bab[(size_t)(c0 + j) * BD + bd];
        }
#pragma unroll
        for (int j = 0; j < 16; ++j) {
            Hinit[(size_t)(c0 + j) * BD + bd] = h;
            h = aa[j] * h + bb[j];
        }
    }
}

__global__ __launch_bounds__(256) void scan_phase_c(
    const float* kw, const float* vw, const float* __restrict__ Hinit,
    float* outp, float* hsec, int tc)
{
    const int bd = blockIdx.x * 256 + threadIdx.x;   // 0..BD-1
    const int c  = blockIdx.y;                       // 0..nc-1
    float h = Hinit[(size_t)c * BD + bd];

    const size_t base = (size_t)c * tc * BD + bd;
    const float* kp = kw + base;
    const float* vp = vw + base;
    float* op = outp + base;
    float* hp = hsec + base + BD;

    float kk[16], vv[16];
#pragma unroll
    for (int j = 0; j < 16; ++j) {
        kk[j] = kp[(size_t)j * BD];
        vv[j] = vp[(size_t)j * BD];
    }
    for (int t0 = 0; t0 < tc; t0 += 16) {
        float kn[16], vn[16];
        if (t0 + 16 < tc) {
#pragma unroll
            for (int j = 0; j < 16; ++j) {          // prefetch BEFORE stores
                kn[j] = kp[(size_t)(t0 + 16 + j) * BD];
                vn[j] = vp[(size_t)(t0 + 16 + j) * BD];
            }
        }
#pragma unroll
        for (int j = 0; j < 16; ++j) {
            h = (1.f - kk[j]) * h + kk[j] * vv[j];
            hp[(size_t)(t0 + j) * BD] = h;
            const float sig = 1.f / (1.f + __expf(-h));
            op[(size_t)(t0 + j) * BD] = h * h * sig;
        }
        if (t0 + 16 < tc) {
#pragma unroll
            for (int j = 0; j < 16; ++j) { kk[j] = kn[j]; vv[j] = vn[j]; }
        }
    }
}

// ---------------------------------------------------------------------------
// Fallback sequential scan (ws too small for chunk buffers).
// ---------------------------------------------------------------------------
__global__ __launch_bounds__(64) void scan_kernel(
    const float* kw, const float* vw, const float* h0,
    float* outp, float* hsec)
{
    const int c = blockIdx.x * 64 + threadIdx.x;   // 0..16383
    float h = h0[c];
    hsec[c] = h;

    const float* kp = kw + c;
    const float* vp = vw + c;
    float* op = outp + c;
    float* hp = hsec + BD + c;

    for (int t = 0; t < T_DIM; t += 8) {
        float kk[8], vv[8];
#pragma unroll
        for (int j = 0; j < 8; ++j) {
            kk[j] = kp[(size_t)(t + j) * BD];
            vv[j] = vp[(size_t)(t + j) * BD];
        }
#pragma unroll
        for (int j = 0; j < 8; ++j) {
            h = (1.f - kk[j]) * h + kk[j] * vv[j];
            hp[(size_t)(t + j) * BD] = h;
            const float sig = 1.f / (1.f + __expf(-h));
            op[(size_t)(t + j) * BD] = h * h * sig;
        }
    }
}

// ---------------------------------------------------------------------------
extern "C" void kernel_launch(void* const* d_in, const int* in_sizes, int n_in,
                              void* d_out, int out_size, void* d_ws, size_t ws_size,
                              hipStream_t stream)
{
    const float* x  = (const float*)d_in[0];   // [T,B,D]
    const float* h0 = (const float*)d_in[1];   // [B,D]
    const float* Wk = (const float*)d_in[2];   // [D,D]
    const float* bk = (const float*)d_in[3];   // [D]
    const float* Wv = (const float*)d_in[4];   // [D,D]
    const float* bv = (const float*)d_in[5];   // [D]

    float* outp = (float*)d_out;               // output section [T,B,D]
    float* hsec = outp + TBD;                  // h section [T+1,B,D]

    // k -> output section, v -> h[1:] section: element-exact in-place (safe,
    // see scan comments). No workspace needed for k/v themselves.
    float* kw = outp;
    float* vw = hsec + BD;

    const size_t bf16_bytes = (TBD + 2 * (size_t)D_DIM * D_DIM) * sizeof(short);

    bool bf16_path = false;
    size_t avail = ws_size;
    char* scan_ws = (char*)d_ws;
    if (ws_size >= bf16_bytes) {
        bf16_path = true;
        avail   -= bf16_bytes;
        scan_ws += bf16_bytes;
    }

    // Pick the largest chunk count whose (Aab,Bab,Hinit) buffers fit.
    int nc = 0;
    if (avail >= 3 * (size_t)128 * BD * sizeof(float))      nc = 128;
    else if (avail >= 3 * (size_t)32 * BD * sizeof(float))  nc = 32;
    const int tc = nc ? T_DIM / nc : 0;

    float* Aab   = nc ? (float*)scan_ws : nullptr;
    float* Bab   = nc ? Aab + (size_t)nc * BD : nullptr;
    float* Hinit = nc ? Bab + (size_t)nc * BD : nullptr;

    if (bf16_path) {
        short* xb  = (short*)d_ws;                       // [T*B, D] bf16
        short* Wkb = xb + TBD;                           // [D, D] bf16
        short* Wvb = Wkb + (size_t)D_DIM * D_DIM;
        cvt_f32_bf16<<<dim3((int)(TBD / 8 / 256)), 256, 0, stream>>>(x, xb, (int)(TBD / 8));
        cvt_f32_bf16<<<dim3(D_DIM * D_DIM / 8 / 256), 256, 0, stream>>>(Wk, Wkb, D_DIM * D_DIM / 8);
        cvt_f32_bf16<<<dim3(D_DIM * D_DIM / 8 / 256), 256, 0, stream>>>(Wv, Wvb, D_DIM * D_DIM / 8);
        gemm_kv_bf16<<<dim3(8, 256, 2), 256, 0, stream>>>(xb, Wkb, bk, Wvb, bv, kw, vw);
    } else {
        gemm_kv_f32src<<<dim3(8, 256, 2), 256, 0, stream>>>(x, Wk, bk, Wv, bv, kw, vw);
    }

    if (nc) {
        scan_phase_a<<<dim3(BD / 256, nc), 256, 0, stream>>>(kw, vw, Aab, Bab, tc);
        scan_phase_b<<<dim3(BD / 256), 256, 0, stream>>>(h0, Aab, Bab, Hinit, hsec, nc);
        scan_phase_c<<<dim3(BD / 256, nc), 256, 0, stream>>>(kw, vw, Hinit, outp, hsec, tc);
    } else {
        scan_kernel<<<dim3(BD / 64), 64, 0, stream>>>(kw, vw, h0, outp, hsec);
    }
}